// Round 1
// baseline (246.202 us; speedup 1.0000x reference)
//
#include <hip/hip_runtime.h>
#include <hip/hip_bf16.h>
#include <math.h>

#define Bb 16
#define Tt 64
#define Ff 64
#define Hh 64
#define NH 4
#define MAXE 2048

// ---------------- Stage 0: deterministic CSR by dst ----------------
__global__ __launch_bounds__(256) void k0_csr(const int* __restrict__ src,
                                              const int* __restrict__ dst,
                                              int E, int* __restrict__ off,
                                              int* __restrict__ csr_src) {
  __shared__ int s_src[MAXE], s_dst[MAXE];
  __shared__ int cnt[Ff], base[Ff];
  int t = threadIdx.x;
  for (int e = t; e < E; e += 256) { s_src[e] = src[e]; s_dst[e] = dst[e]; }
  if (t < Ff) cnt[t] = 0;
  __syncthreads();
  for (int e = t; e < E; e += 256) atomicAdd(&cnt[s_dst[e]], 1);
  __syncthreads();
  if (t == 0) {
    int s = 0;
    for (int i = 0; i < Ff; ++i) { base[i] = s; off[i] = s; s += cnt[i]; }
    off[Ff] = s;
  }
  __syncthreads();
  if (t < Ff) {
    int pos = base[t];
    for (int e = 0; e < E; ++e)
      if (s_dst[e] == t) csr_src[pos++] = s_src[e];
  }
}

// ---------------- Stage 1: enc + GAT per (b,t) graph ----------------
__global__ __launch_bounds__(256) void k1_enc_gat(
    const float* __restrict__ hist, const float* __restrict__ W_enc,
    const float* __restrict__ b_enc, const float* __restrict__ W_gat,
    const float* __restrict__ attn_l, const float* __restrict__ attn_r,
    const float* __restrict__ b_gat, const int* __restrict__ off,
    const int* __restrict__ csr_src, int E, float* __restrict__ g_out) {
  __shared__ __align__(16) float enc_s[Ff][68];
  __shared__ __align__(16) float feat_s[Ff][68];
  __shared__ __align__(16) float Wg[Hh][64];
  __shared__ float el_s[Ff][NH], er_s[Ff][NH];
  __shared__ float al_s[64], ar_s[64], bg_s[64];
  __shared__ int off_s[Ff + 1];
  __shared__ int csr_s[MAXE];
  int bt = blockIdx.x;
  int t = threadIdx.x;
  for (int i = t; i < Hh * 64 / 4; i += 256)
    ((float4*)Wg)[i] = ((const float4*)W_gat)[i];
  if (t < 64) { al_s[t] = attn_l[t]; ar_s[t] = attn_r[t]; bg_s[t] = b_gat[t]; }
  if (t < Ff + 1) off_s[t] = off[t];
  for (int e = t; e < E; e += 256) csr_s[e] = csr_src[e];

  int n = t >> 2, hb = t & 3;
  float xv = hist[bt * Ff + n];
#pragma unroll
  for (int c = 0; c < 4; ++c) {
    float4 w = *(const float4*)&W_enc[n * Hh + hb * 16 + c * 4];
    float4 bv = *(const float4*)&b_enc[n * Hh + hb * 16 + c * 4];
    float4 r;
    r.x = fmaf(xv, w.x, bv.x); r.y = fmaf(xv, w.y, bv.y);
    r.z = fmaf(xv, w.z, bv.z); r.w = fmaf(xv, w.w, bv.w);
    *(float4*)&enc_s[n][hb * 16 + c * 4] = r;
  }
  __syncthreads();

  // feat = enc @ W_gat ; thread (n, hb) computes feat[n][hb*16 .. +15]
  float acc[16];
#pragma unroll
  for (int j = 0; j < 16; ++j) acc[j] = 0.f;
  for (int k = 0; k < Hh; ++k) {
    float ev = enc_s[n][k];
#pragma unroll
    for (int c = 0; c < 4; ++c) {
      float4 w = *(const float4*)&Wg[k][hb * 16 + c * 4];
      acc[c * 4 + 0] = fmaf(ev, w.x, acc[c * 4 + 0]);
      acc[c * 4 + 1] = fmaf(ev, w.y, acc[c * 4 + 1]);
      acc[c * 4 + 2] = fmaf(ev, w.z, acc[c * 4 + 2]);
      acc[c * 4 + 3] = fmaf(ev, w.w, acc[c * 4 + 3]);
    }
  }
  float sl = 0.f, sr = 0.f;
#pragma unroll
  for (int j = 0; j < 16; ++j) {
    sl = fmaf(acc[j], al_s[hb * 16 + j], sl);
    sr = fmaf(acc[j], ar_s[hb * 16 + j], sr);
  }
  el_s[n][hb] = sl;
  er_s[n][hb] = sr;
#pragma unroll
  for (int c = 0; c < 4; ++c) {
    float4 o;
    o.x = acc[c * 4 + 0]; o.y = acc[c * 4 + 1];
    o.z = acc[c * 4 + 2]; o.w = acc[c * 4 + 3];
    *(float4*)&feat_s[n][hb * 16 + c * 4] = o;
  }
  __syncthreads();

  // edge phase: thread (d = n, head = hb)
  int d = n, hd = hb;
  int o0 = off_s[d], o1 = off_s[d + 1];
  float erd = er_s[d][hd];
  float m = -1e30f;
  for (int e = o0; e < o1; ++e) {
    int s = csr_s[e];
    float v = el_s[s][hd] + erd;
    v = v > 0.f ? v : 0.2f * v;
    m = fmaxf(m, v);
  }
  float den = 0.f;
  float mg[16];
#pragma unroll
  for (int j = 0; j < 16; ++j) mg[j] = 0.f;
  for (int e = o0; e < o1; ++e) {
    int s = csr_s[e];
    float v = el_s[s][hd] + erd;
    v = v > 0.f ? v : 0.2f * v;
    float p = __expf(v - m);
    den += p;
#pragma unroll
    for (int c = 0; c < 4; ++c) {
      float4 fv = *(const float4*)&feat_s[s][hd * 16 + c * 4];
      mg[c * 4 + 0] = fmaf(p, fv.x, mg[c * 4 + 0]);
      mg[c * 4 + 1] = fmaf(p, fv.y, mg[c * 4 + 1]);
      mg[c * 4 + 2] = fmaf(p, fv.z, mg[c * 4 + 2]);
      mg[c * 4 + 3] = fmaf(p, fv.w, mg[c * 4 + 3]);
    }
  }
  float inv = 1.f / den;
  float* gp = g_out + (size_t)(bt * Ff + d) * Hh + hd * 16;
#pragma unroll
  for (int c = 0; c < 4; ++c) {
    float4 o;
    o.x = mg[c * 4 + 0] * inv + bg_s[hd * 16 + c * 4 + 0];
    o.y = mg[c * 4 + 1] * inv + bg_s[hd * 16 + c * 4 + 1];
    o.z = mg[c * 4 + 2] * inv + bg_s[hd * 16 + c * 4 + 2];
    o.w = mg[c * 4 + 3] * inv + bg_s[hd * 16 + c * 4 + 3];
    *(float4*)&gp[c * 4] = o;
  }
}

// ---------------- Stage 2: per-feature GRU (W in registers, DPP reduce) ----
__device__ __forceinline__ float qsum(float v) {
  v += __int_as_float(__builtin_amdgcn_mov_dpp(__float_as_int(v), 0xB1, 0xF, 0xF, true));
  v += __int_as_float(__builtin_amdgcn_mov_dpp(__float_as_int(v), 0x4E, 0xF, 0xF, true));
  return v;
}

__global__ __launch_bounds__(256) void k2_gru(
    const float* __restrict__ W_ih, const float* __restrict__ W_hh,
    const float* __restrict__ b_ih, const float* __restrict__ b_hh,
    float* __restrict__ hid) {  // hid holds g on entry; overwritten with h
  int f = blockIdx.x >> 2;
  int b0 = (blockIdx.x & 3) * 4;
  int t = threadIdx.x;
  int h = t >> 2, kg = t & 3;
  __shared__ __align__(16) float x_s[4][64];
  __shared__ __align__(16) float h_s[4][64];
  const float* Wi = W_ih + f * 192 * 64;
  const float* Wh = W_hh + f * 192 * 64;
  float wi[3][16], wh[3][16];
#pragma unroll
  for (int g = 0; g < 3; ++g) {
#pragma unroll
    for (int c = 0; c < 4; ++c) {
      *(float4*)&wi[g][c * 4] = *(const float4*)&Wi[(g * 64 + h) * 64 + kg * 16 + c * 4];
      *(float4*)&wh[g][c * 4] = *(const float4*)&Wh[(g * 64 + h) * 64 + kg * 16 + c * 4];
    }
  }
  float bi0 = b_ih[f * 192 + h], bi1 = b_ih[f * 192 + 64 + h], bi2 = b_ih[f * 192 + 128 + h];
  float bh0 = b_hh[f * 192 + h], bh1 = b_hh[f * 192 + 64 + h], bh2 = b_hh[f * 192 + 128 + h];
  float hreg = 0.f;
  int bl = t >> 6, kk = t & 63;
  h_s[bl][kk] = 0.f;

  for (int ts = 0; ts < Tt; ++ts) {
    float xv = hid[((size_t)(b0 + bl) * Tt + ts) * (Ff * Hh) + f * Hh + kk];
    x_s[bl][kk] = xv;
    __syncthreads();  // x visible; prev h writes visible; prev x readers done
    float ar_[4], az_[4], axn_[4], ahn_[4];
#pragma unroll
    for (int b = 0; b < 4; ++b) { ar_[b] = 0.f; az_[b] = 0.f; axn_[b] = 0.f; ahn_[b] = 0.f; }
#pragma unroll
    for (int b = 0; b < 4; ++b) {
#pragma unroll
      for (int c = 0; c < 4; ++c) {
        float xc[4], hc[4];
        *(float4*)xc = *(const float4*)&x_s[b][kg * 16 + c * 4];
        *(float4*)hc = *(const float4*)&h_s[b][kg * 16 + c * 4];
#pragma unroll
        for (int e = 0; e < 4; ++e) {
          int k = c * 4 + e;
          ar_[b]  = fmaf(xc[e], wi[0][k], ar_[b]);
          ar_[b]  = fmaf(hc[e], wh[0][k], ar_[b]);
          az_[b]  = fmaf(xc[e], wi[1][k], az_[b]);
          az_[b]  = fmaf(hc[e], wh[1][k], az_[b]);
          axn_[b] = fmaf(xc[e], wi[2][k], axn_[b]);
          ahn_[b] = fmaf(hc[e], wh[2][k], ahn_[b]);
        }
      }
    }
#pragma unroll
    for (int b = 0; b < 4; ++b) {
      ar_[b] = qsum(ar_[b]); az_[b] = qsum(az_[b]);
      axn_[b] = qsum(axn_[b]); ahn_[b] = qsum(ahn_[b]);
    }
    __syncthreads();  // all h_s / x_s reads of this step done
    float sr_ = kg == 0 ? ar_[0] : (kg == 1 ? ar_[1] : (kg == 2 ? ar_[2] : ar_[3]));
    float sz_ = kg == 0 ? az_[0] : (kg == 1 ? az_[1] : (kg == 2 ? az_[2] : az_[3]));
    float sxn = kg == 0 ? axn_[0] : (kg == 1 ? axn_[1] : (kg == 2 ? axn_[2] : axn_[3]));
    float shn = kg == 0 ? ahn_[0] : (kg == 1 ? ahn_[1] : (kg == 2 ? ahn_[2] : ahn_[3]));
    float r = 1.f / (1.f + __expf(-(sr_ + bi0 + bh0)));
    float z = 1.f / (1.f + __expf(-(sz_ + bi1 + bh1)));
    float nn = tanhf(sxn + bi2 + r * (shn + bh2));
    float hn2 = (1.f - z) * nn + z * hreg;
    hreg = hn2;
    h_s[kg][h] = hn2;
    hid[((size_t)(b0 + kg) * Tt + ts) * (Ff * Hh) + f * Hh + h] = hn2;
  }
}

// ---------------- Stage 3: decode ----------------
__global__ __launch_bounds__(256) void k3_dec(const float* __restrict__ hid,
                                              const float* __restrict__ W_dec,
                                              const float* __restrict__ b_dec,
                                              float* __restrict__ ans) {
  int idx = blockIdx.x * 256 + threadIdx.x;
  int fo = idx & 63;
  const float* hr = hid + (size_t)idx * 64;
  const float* wr = W_dec + fo * 64;
  float s = b_dec[fo];
#pragma unroll
  for (int c = 0; c < 16; ++c) {
    float4 hv = *(const float4*)&hr[c * 4];
    float4 wv = *(const float4*)&wr[c * 4];
    s += hv.x * wv.x + hv.y * wv.y + hv.z * wv.z + hv.w * wv.w;
  }
  ans[idx] = s;
}

extern "C" void kernel_launch(void* const* d_in, const int* in_sizes, int n_in,
                              void* d_out, int out_size, void* d_ws, size_t ws_size,
                              hipStream_t stream) {
  const float* hist  = (const float*)d_in[0];
  const int* src     = (const int*)d_in[1];
  const int* dst     = (const int*)d_in[2];
  const float* W_enc = (const float*)d_in[3];
  const float* b_enc = (const float*)d_in[4];
  const float* W_gat = (const float*)d_in[5];
  const float* attn_l = (const float*)d_in[6];
  const float* attn_r = (const float*)d_in[7];
  const float* b_gat = (const float*)d_in[8];
  const float* W_ih  = (const float*)d_in[9];
  const float* W_hh  = (const float*)d_in[10];
  const float* b_ih  = (const float*)d_in[11];
  const float* b_hh  = (const float*)d_in[12];
  const float* W_dec = (const float*)d_in[13];
  const float* b_dec = (const float*)d_in[14];
  int E = in_sizes[1];

  float* ans = (float*)d_out;
  float* hid = (float*)d_out + Bb * Tt * Ff;  // [B,T,F,H]; holds g then h
  int* off = (int*)d_ws;
  int* csr = off + Ff + 1;

  hipLaunchKernelGGL(k0_csr, dim3(1), dim3(256), 0, stream, src, dst, E, off, csr);
  hipLaunchKernelGGL(k1_enc_gat, dim3(Bb * Tt), dim3(256), 0, stream,
                     hist, W_enc, b_enc, W_gat, attn_l, attn_r, b_gat, off, csr, E, hid);
  hipLaunchKernelGGL(k2_gru, dim3(Ff * 4), dim3(256), 0, stream,
                     W_ih, W_hh, b_ih, b_hh, hid);
  hipLaunchKernelGGL(k3_dec, dim3(Bb * Tt * Ff / 256), dim3(256), 0, stream,
                     hid, W_dec, b_dec, ans);
}

// Round 2
// 212.075 us; speedup vs baseline: 1.1609x; 1.1609x over previous
//
#include <hip/hip_runtime.h>
#include <hip/hip_bf16.h>
#include <math.h>

#define Bb 16
#define Tt 64
#define Ff 64
#define Hh 64
#define MAXE 2048
#define PAD 68

// ---------------- Stage 0: CSR + input-independent tables ----------------
__global__ __launch_bounds__(256) void k0_prep(
    const int* __restrict__ src, const int* __restrict__ dst, int E,
    const float* __restrict__ W_enc, const float* __restrict__ b_enc,
    const float* __restrict__ W_gat, const float* __restrict__ attn_l,
    const float* __restrict__ attn_r,
    int* __restrict__ off, int* __restrict__ csr,
    float* __restrict__ A, float* __restrict__ Bc,
    float* __restrict__ aA, float* __restrict__ aB,
    float* __restrict__ rA, float* __restrict__ rB) {
  __shared__ int s_src[MAXE], s_dst[MAXE];
  __shared__ int cnt[Ff], base[Ff];
  __shared__ __align__(16) float We[64][64], Be[64][64], Wg[64][64];
  __shared__ __align__(16) float As[64][64], Bs[64][64];
  __shared__ float al_s[64], ar_s[64];
  int t = threadIdx.x;
  for (int e = t; e < E; e += 256) { s_src[e] = src[e]; s_dst[e] = dst[e]; }
  if (t < Ff) cnt[t] = 0;
  for (int i = t; i < 1024; i += 256) {
    ((float4*)We)[i] = ((const float4*)W_enc)[i];
    ((float4*)Be)[i] = ((const float4*)b_enc)[i];
    ((float4*)Wg)[i] = ((const float4*)W_gat)[i];
  }
  if (t < 64) { al_s[t] = attn_l[t]; ar_s[t] = attn_r[t]; }
  __syncthreads();
  for (int e = t; e < E; e += 256) atomicAdd(&cnt[s_dst[e]], 1);
  __syncthreads();
  if (t == 0) {
    int s = 0;
    for (int i = 0; i < Ff; ++i) { base[i] = s; off[i] = s; s += cnt[i]; }
    off[Ff] = s;
  }
  __syncthreads();
  if (t < Ff) {
    int pos = base[t];
    for (int e = 0; e < E; ++e)
      if (s_dst[e] == t) csr[pos++] = s_src[e];
  }
  // A = W_enc @ W_gat, Bc = b_enc @ W_gat
  int n = t >> 2, q = t & 3;
  float accA[16], accB[16];
#pragma unroll
  for (int j = 0; j < 16; ++j) { accA[j] = 0.f; accB[j] = 0.f; }
  for (int k = 0; k < 64; ++k) {
    float we = We[n][k], be = Be[n][k];
#pragma unroll
    for (int c = 0; c < 4; ++c) {
      float4 wg = *(const float4*)&Wg[k][q * 16 + c * 4];
      accA[c*4+0] = fmaf(we, wg.x, accA[c*4+0]); accB[c*4+0] = fmaf(be, wg.x, accB[c*4+0]);
      accA[c*4+1] = fmaf(we, wg.y, accA[c*4+1]); accB[c*4+1] = fmaf(be, wg.y, accB[c*4+1]);
      accA[c*4+2] = fmaf(we, wg.z, accA[c*4+2]); accB[c*4+2] = fmaf(be, wg.z, accB[c*4+2]);
      accA[c*4+3] = fmaf(we, wg.w, accA[c*4+3]); accB[c*4+3] = fmaf(be, wg.w, accB[c*4+3]);
    }
  }
#pragma unroll
  for (int c = 0; c < 4; ++c) {
    float4 va, vb;
    va.x = accA[c*4+0]; va.y = accA[c*4+1]; va.z = accA[c*4+2]; va.w = accA[c*4+3];
    vb.x = accB[c*4+0]; vb.y = accB[c*4+1]; vb.z = accB[c*4+2]; vb.w = accB[c*4+3];
    *(float4*)&As[n][q*16 + c*4] = va;
    *(float4*)&Bs[n][q*16 + c*4] = vb;
    *(float4*)&A[n*64 + q*16 + c*4] = va;
    *(float4*)&Bc[n*64 + q*16 + c*4] = vb;
  }
  __syncthreads();
  // attention scalar tables: aA[n,h] = A[n, h*16:+16] . attn_l[h] etc.
  float sa = 0.f, sb = 0.f, sra = 0.f, srb = 0.f;
#pragma unroll
  for (int j = 0; j < 16; ++j) {
    float alv = al_s[q*16 + j], arv = ar_s[q*16 + j];
    float av = As[n][q*16 + j], bv = Bs[n][q*16 + j];
    sa  = fmaf(av, alv, sa);  sb  = fmaf(bv, alv, sb);
    sra = fmaf(av, arv, sra); srb = fmaf(bv, arv, srb);
  }
  aA[t] = sa; aB[t] = sb; rA[t] = sra; rB[t] = srb;
}

// ---------------- Stage 1: GAT via tables, per (b,t) ----------------
__global__ __launch_bounds__(256) void k1_gat(
    const float* __restrict__ hist, const float* __restrict__ A,
    const float* __restrict__ Bc, const float* __restrict__ aA,
    const float* __restrict__ aB, const float* __restrict__ rA,
    const float* __restrict__ rB, const float* __restrict__ b_gat,
    const int* __restrict__ off, const int* __restrict__ csr, int E,
    float* __restrict__ g_out) {
  __shared__ __align__(16) float As[64][PAD];
  __shared__ __align__(16) float Bs[64][PAD];
  __shared__ float x_s[64];
  __shared__ float el_s[64][4], er_s[64][4];
  __shared__ float bg[64];
  __shared__ int off_s[Ff + 1];
  __shared__ int csr_s[1152];
  int bt = blockIdx.x, t = threadIdx.x;
  for (int i = t; i < 1024; i += 256) {
    int r = i >> 4, ch = i & 15;
    int chs = ch ^ (r & 7);  // XOR-swizzle: spread banks across random-row reads
    *(float4*)&As[r][chs * 4] = ((const float4*)A)[i];
    *(float4*)&Bs[r][chs * 4] = ((const float4*)Bc)[i];
  }
  if (t < 64) { x_s[t] = hist[bt * 64 + t]; bg[t] = b_gat[t]; }
  if (t < Ff + 1) off_s[t] = off[t];
  for (int e = t; e < E; e += 256) csr_s[e] = csr[e];
  __syncthreads();
  int n = t >> 2, h = t & 3;
  {
    float xn = x_s[n];
    el_s[n][h] = fmaf(xn, aA[t], aB[t]);
    er_s[n][h] = fmaf(xn, rA[t], rB[t]);
  }
  __syncthreads();
  int o0 = off_s[n], o1 = off_s[n + 1];
  float erd = er_s[n][h];
  float m = -1e30f;
  for (int e = o0; e < o1; ++e) {
    int s = csr_s[e];
    float v = el_s[s][h] + erd;
    v = v > 0.f ? v : 0.2f * v;
    m = fmaxf(m, v);
  }
  float den = 0.f;
  float acc[16];
#pragma unroll
  for (int j = 0; j < 16; ++j) acc[j] = 0.f;
  for (int e = o0; e < o1; ++e) {
    int s = csr_s[e];
    float v = el_s[s][h] + erd;
    v = v > 0.f ? v : 0.2f * v;
    float p = __expf(v - m);
    den += p;
    float xs = x_s[s];
    int k = s & 7;
    int rb = s * PAD;
#pragma unroll
    for (int c = 0; c < 4; ++c) {
      int ch = (h * 4 + c) ^ k;
      float4 a4 = *(const float4*)&As[0][rb + ch * 4];
      float4 b4 = *(const float4*)&Bs[0][rb + ch * 4];
      acc[c*4+0] = fmaf(p, fmaf(xs, a4.x, b4.x), acc[c*4+0]);
      acc[c*4+1] = fmaf(p, fmaf(xs, a4.y, b4.y), acc[c*4+1]);
      acc[c*4+2] = fmaf(p, fmaf(xs, a4.z, b4.z), acc[c*4+2]);
      acc[c*4+3] = fmaf(p, fmaf(xs, a4.w, b4.w), acc[c*4+3]);
    }
  }
  float inv = 1.f / den;
  float* gp = g_out + bt * 4096 + n * 64 + h * 16;
#pragma unroll
  for (int c = 0; c < 4; ++c) {
    float4 o;
    o.x = fmaf(acc[c*4+0], inv, bg[h*16 + c*4 + 0]);
    o.y = fmaf(acc[c*4+1], inv, bg[h*16 + c*4 + 1]);
    o.z = fmaf(acc[c*4+2], inv, bg[h*16 + c*4 + 2]);
    o.w = fmaf(acc[c*4+3], inv, bg[h*16 + c*4 + 3]);
    *(float4*)&gp[c * 4] = o;
  }
}

// ---------------- Stage 2: GRU, one (f,b) chain per block + fused decode ----
__device__ __forceinline__ float qsum(float v) {
  v += __int_as_float(__builtin_amdgcn_mov_dpp(__float_as_int(v), 0xB1, 0xF, 0xF, true));
  v += __int_as_float(__builtin_amdgcn_mov_dpp(__float_as_int(v), 0x4E, 0xF, 0xF, true));
  return v;
}

__global__ __launch_bounds__(256, 4) void k2_gru(
    const float* __restrict__ W_ih, const float* __restrict__ W_hh,
    const float* __restrict__ b_ih, const float* __restrict__ b_hh,
    const float* __restrict__ W_dec, const float* __restrict__ b_dec,
    float* __restrict__ hid, float* __restrict__ ans) {
  int blk = blockIdx.x;
  int f = blk & 63, b = blk >> 6;  // same-f blocks land on same XCD
  int t = threadIdx.x;
  int h = t >> 2, kg = t & 3;
  __shared__ __align__(16) float x_s[2][64];
  __shared__ __align__(16) float h_s[64];
  const float* Wi = W_ih + f * 12288;
  const float* Wh = W_hh + f * 12288;
  float wi[3][16], wh[3][16];
#pragma unroll
  for (int g = 0; g < 3; ++g)
#pragma unroll
    for (int c = 0; c < 4; ++c) {
      *(float4*)&wi[g][c*4] = *(const float4*)&Wi[(g*64 + h)*64 + kg*16 + c*4];
      *(float4*)&wh[g][c*4] = *(const float4*)&Wh[(g*64 + h)*64 + kg*16 + c*4];
    }
  float bR  = b_ih[f*192 + h]      + b_hh[f*192 + h];
  float bZ  = b_ih[f*192 + 64 + h] + b_hh[f*192 + 64 + h];
  float bXN = b_ih[f*192 + 128 + h];
  float bHN = b_hh[f*192 + 128 + h];
  float wd = 0.f, bd = 0.f;
  if (t >= 64 && t < 128) wd = W_dec[f*64 + (t - 64)];
  if (t == 64) bd = b_dec[f];
  int xbase = (b * 64) * 4096 + f * 64;
  if (t < 64) { x_s[0][t] = hid[xbase + t]; h_s[t] = 0.f; }
  __syncthreads();
  float hreg = 0.f;
  for (int ts = 0; ts < 64; ++ts) {
    int cur = ts & 1;
    float xn = 0.f;
    if (t < 64 && ts < 63) xn = hid[xbase + (ts + 1) * 4096 + t];  // prefetch
    float ar = 0.f, az = 0.f, axn = 0.f, ahn = 0.f;
#pragma unroll
    for (int c = 0; c < 4; ++c) {
      float xc[4], hc[4];
      *(float4*)xc = *(const float4*)&x_s[cur][kg*16 + c*4];
      *(float4*)hc = *(const float4*)&h_s[kg*16 + c*4];
#pragma unroll
      for (int e2 = 0; e2 < 4; ++e2) {
        int k = c * 4 + e2;
        ar  = fmaf(xc[e2], wi[0][k], ar);
        ar  = fmaf(hc[e2], wh[0][k], ar);
        az  = fmaf(xc[e2], wi[1][k], az);
        az  = fmaf(hc[e2], wh[1][k], az);
        axn = fmaf(xc[e2], wi[2][k], axn);
        ahn = fmaf(hc[e2], wh[2][k], ahn);
      }
    }
    ar = qsum(ar); az = qsum(az); axn = qsum(axn); ahn = qsum(ahn);
    float r = 1.f / (1.f + __expf(-(ar + bR)));
    float z = 1.f / (1.f + __expf(-(az + bZ)));
    float pre = fmaf(r, ahn + bHN, axn + bXN);
    float en = __expf(-2.f * pre);
    float nn = 2.f / (1.f + en) - 1.f;        // tanh(pre)
    float hnew = fmaf(z, hreg - nn, nn);      // (1-z)n + z h
    hreg = hnew;
    if (t < 64 && ts < 63) x_s[cur ^ 1][t] = xn;
    __syncthreads();                // all reads of h_s/x_s for this step done
    if (kg == 0) h_s[h] = hnew;
    __syncthreads();                // h_s = h(ts)
    if (t >= 64 && t < 128) {       // fused decode (wave 1)
      float part = h_s[t - 64] * wd;
      part += __shfl_xor(part, 1);
      part += __shfl_xor(part, 2);
      part += __shfl_xor(part, 4);
      part += __shfl_xor(part, 8);
      part += __shfl_xor(part, 16);
      part += __shfl_xor(part, 32);
      if (t == 64) ans[(b * 64 + ts) * 64 + f] = part + bd;
    }
    if (t >= 128 && t < 192)        // coalesced h store (wave 2)
      hid[xbase + ts * 4096 + (t - 128)] = h_s[t - 128];
  }
}

extern "C" void kernel_launch(void* const* d_in, const int* in_sizes, int n_in,
                              void* d_out, int out_size, void* d_ws, size_t ws_size,
                              hipStream_t stream) {
  const float* hist  = (const float*)d_in[0];
  const int* src     = (const int*)d_in[1];
  const int* dst     = (const int*)d_in[2];
  const float* W_enc = (const float*)d_in[3];
  const float* b_enc = (const float*)d_in[4];
  const float* W_gat = (const float*)d_in[5];
  const float* attn_l = (const float*)d_in[6];
  const float* attn_r = (const float*)d_in[7];
  const float* b_gat = (const float*)d_in[8];
  const float* W_ih  = (const float*)d_in[9];
  const float* W_hh  = (const float*)d_in[10];
  const float* b_ih  = (const float*)d_in[11];
  const float* b_hh  = (const float*)d_in[12];
  const float* W_dec = (const float*)d_in[13];
  const float* b_dec = (const float*)d_in[14];
  int E = in_sizes[1];

  float* ans = (float*)d_out;
  float* hid = (float*)d_out + Bb * Tt * Ff;  // [B,T,F,H]; holds g then h

  int* off = (int*)d_ws;                    // 65 used (reserve 256)
  int* csr = off + 256;                     // E used (reserve 2048)
  float* A  = (float*)(csr + 2048);         // 4096
  float* Bc = A + 4096;                     // 4096
  float* aA = Bc + 4096;                    // 256
  float* aB = aA + 256;
  float* rA = aB + 256;
  float* rB = rA + 256;

  hipLaunchKernelGGL(k0_prep, dim3(1), dim3(256), 0, stream,
                     src, dst, E, W_enc, b_enc, W_gat, attn_l, attn_r,
                     off, csr, A, Bc, aA, aB, rA, rB);
  hipLaunchKernelGGL(k1_gat, dim3(Bb * Tt), dim3(256), 0, stream,
                     hist, A, Bc, aA, aB, rA, rB, b_gat, off, csr, E, hid);
  hipLaunchKernelGGL(k2_gru, dim3(Ff * Bb), dim3(256), 0, stream,
                     W_ih, W_hh, b_ih, b_hh, W_dec, b_dec, hid, ans);
}

// Round 3
// 209.475 us; speedup vs baseline: 1.1753x; 1.0124x over previous
//
#include <hip/hip_runtime.h>
#include <hip/hip_bf16.h>
#include <math.h>

#define Bb 16
#define Tt 64
#define Ff 64
#define Hh 64
#define MAXE 2048

// ---------------- k0: CSR + input-independent tables (bg folded into Bc) ----
__global__ __launch_bounds__(256) void k0_prep(
    const int* __restrict__ src, const int* __restrict__ dst, int E,
    const float* __restrict__ W_enc, const float* __restrict__ b_enc,
    const float* __restrict__ W_gat, const float* __restrict__ attn_l,
    const float* __restrict__ attn_r, const float* __restrict__ b_gat,
    int* __restrict__ off, int* __restrict__ csr,
    float* __restrict__ A, float* __restrict__ Bc,
    float* __restrict__ aA, float* __restrict__ aB,
    float* __restrict__ rA, float* __restrict__ rB) {
  __shared__ int s_src[MAXE], s_dst[MAXE];
  __shared__ int cnt[Ff], base[Ff];
  __shared__ __align__(16) float We[64][64], Be[64][64], Wg[64][64];
  __shared__ __align__(16) float As[64][64], Bs[64][64];
  __shared__ float al_s[64], ar_s[64], bg_s[64];
  int t = threadIdx.x;
  for (int e = t; e < E; e += 256) { s_src[e] = src[e]; s_dst[e] = dst[e]; }
  if (t < Ff) cnt[t] = 0;
  for (int i = t; i < 1024; i += 256) {
    ((float4*)We)[i] = ((const float4*)W_enc)[i];
    ((float4*)Be)[i] = ((const float4*)b_enc)[i];
    ((float4*)Wg)[i] = ((const float4*)W_gat)[i];
  }
  if (t < 64) { al_s[t] = attn_l[t]; ar_s[t] = attn_r[t]; bg_s[t] = b_gat[t]; }
  __syncthreads();
  for (int e = t; e < E; e += 256) atomicAdd(&cnt[s_dst[e]], 1);
  __syncthreads();
  if (t == 0) {
    int s = 0;
    for (int i = 0; i < Ff; ++i) { base[i] = s; off[i] = s; s += cnt[i]; }
    off[Ff] = s;
  }
  __syncthreads();
  if (t < Ff) {
    int pos = base[t];
    for (int e = 0; e < E; ++e)
      if (s_dst[e] == t) csr[pos++] = s_src[e];
  }
  // A = W_enc @ W_gat ; Bc = b_enc @ W_gat  (global Bc has b_gat folded in)
  int n = t >> 2, q = t & 3;
  float accA[16], accB[16];
#pragma unroll
  for (int j = 0; j < 16; ++j) { accA[j] = 0.f; accB[j] = 0.f; }
  for (int k = 0; k < 64; ++k) {
    float we = We[n][k], be = Be[n][k];
#pragma unroll
    for (int c = 0; c < 4; ++c) {
      float4 wg = *(const float4*)&Wg[k][q * 16 + c * 4];
      accA[c*4+0] = fmaf(we, wg.x, accA[c*4+0]); accB[c*4+0] = fmaf(be, wg.x, accB[c*4+0]);
      accA[c*4+1] = fmaf(we, wg.y, accA[c*4+1]); accB[c*4+1] = fmaf(be, wg.y, accB[c*4+1]);
      accA[c*4+2] = fmaf(we, wg.z, accA[c*4+2]); accB[c*4+2] = fmaf(be, wg.z, accB[c*4+2]);
      accA[c*4+3] = fmaf(we, wg.w, accA[c*4+3]); accB[c*4+3] = fmaf(be, wg.w, accB[c*4+3]);
    }
  }
#pragma unroll
  for (int c = 0; c < 4; ++c) {
    float4 va, vb, vbg;
    va.x = accA[c*4+0]; va.y = accA[c*4+1]; va.z = accA[c*4+2]; va.w = accA[c*4+3];
    vb.x = accB[c*4+0]; vb.y = accB[c*4+1]; vb.z = accB[c*4+2]; vb.w = accB[c*4+3];
    vbg.x = vb.x + bg_s[q*16+c*4+0]; vbg.y = vb.y + bg_s[q*16+c*4+1];
    vbg.z = vb.z + bg_s[q*16+c*4+2]; vbg.w = vb.w + bg_s[q*16+c*4+3];
    *(float4*)&As[n][q*16 + c*4] = va;
    *(float4*)&Bs[n][q*16 + c*4] = vb;          // unfolded (for attn tables)
    *(float4*)&A[n*64 + q*16 + c*4] = va;
    *(float4*)&Bc[n*64 + q*16 + c*4] = vbg;     // folded (+b_gat)
  }
  __syncthreads();
  // attention scalar tables: el[n,h](x) = x*aA[n,h] + aB[n,h]; er likewise
  float sa = 0.f, sb = 0.f, sra = 0.f, srb = 0.f;
#pragma unroll
  for (int j = 0; j < 16; ++j) {
    float alv = al_s[q*16 + j], arv = ar_s[q*16 + j];
    float av = As[n][q*16 + j], bv = Bs[n][q*16 + j];
    sa  = fmaf(av, alv, sa);  sb  = fmaf(bv, alv, sb);
    sra = fmaf(av, arv, sra); srb = fmaf(bv, arv, srb);
  }
  aA[t] = sa; aB[t] = sb; rA[t] = sra; rB[t] = srb;
}

// ---------------- fused: GAT(node f only) + GRU + decode, per (f,b) ----------
__device__ __forceinline__ float qsum(float v) {
  v += __int_as_float(__builtin_amdgcn_mov_dpp(__float_as_int(v), 0xB1, 0xF, 0xF, true));
  v += __int_as_float(__builtin_amdgcn_mov_dpp(__float_as_int(v), 0x4E, 0xF, 0xF, true));
  return v;
}

__global__ __launch_bounds__(256, 4) void k_fused(
    const float* __restrict__ hist, const float* __restrict__ Ag,
    const float* __restrict__ Bg, const float* __restrict__ aAg,
    const float* __restrict__ aBg, const float* __restrict__ rAg,
    const float* __restrict__ rBg, const int* __restrict__ off,
    const int* __restrict__ csr,
    const float* __restrict__ W_ih, const float* __restrict__ W_hh,
    const float* __restrict__ b_ih, const float* __restrict__ b_hh,
    const float* __restrict__ W_dec, const float* __restrict__ b_dec,
    float* __restrict__ hid, float* __restrict__ ans) {
  __shared__ __align__(16) float slab[4096];      // x rows, then g rows (XOR-swizzled chunks)
  __shared__ __align__(16) float h_s[2][64];
  __shared__ __align__(16) float hbuf[2][8][64];
  __shared__ float aA_s[256], aB_s[256];
  __shared__ int csr_s[128];
  int blk = blockIdx.x;
  int f = blk & 63, b = blk >> 6;
  int t = threadIdx.x;

  // ---- stage x slab (hist[b] 16KB, swizzled), tables, csr ----
  const float* histb = hist + (size_t)b * 4096;
#pragma unroll
  for (int r = 0; r < 4; ++r) {
    int g4 = r * 256 + t;              // float4 index
    float4 v = ((const float4*)histb)[g4];
    int row = g4 >> 4, ch = g4 & 15;
    ((float4*)slab)[(row << 4) + (ch ^ (row & 7))] = v;
  }
  if (t < 64) {
    ((float4*)aA_s)[t] = ((const float4*)aAg)[t];
    ((float4*)aB_s)[t] = ((const float4*)aBg)[t];
    h_s[0][t] = 0.f;
  }
  int o0 = off[f], deg = off[f + 1] - o0;
  if (t < deg && t < 128) csr_s[t] = csr[o0 + t];
  int tts = t >> 2, hh = t & 3;
  float rAf = rAg[(f << 2) + hh], rBf = rBg[(f << 2) + hh];
  __syncthreads();

  // ---- GAT for dst=f, all 64 timesteps: thread (tts, hh) -> g[tts][hh*16..+15]
  int s7 = tts & 7;
  float xf = slab[(tts << 6) + ((((f >> 2) ^ s7) << 2) | (f & 3))];
  float er = fmaf(xf, rAf, rBf);
  float m = -1e30f;
  for (int i = 0; i < deg; ++i) {
    int s = (i < 128) ? csr_s[i] : csr[o0 + i];
    float xs = slab[(tts << 6) + ((((s >> 2) ^ s7) << 2) | (s & 3))];
    float e = fmaf(xs, aA_s[(s << 2) + hh], aB_s[(s << 2) + hh]) + er;
    e = e > 0.f ? e : 0.2f * e;
    m = fmaxf(m, e);
  }
  float acc[16];
#pragma unroll
  for (int j = 0; j < 16; ++j) acc[j] = 0.f;
  float den = 0.f;
  for (int i = 0; i < deg; ++i) {
    int s = (i < 128) ? csr_s[i] : csr[o0 + i];
    float xs = slab[(tts << 6) + ((((s >> 2) ^ s7) << 2) | (s & 3))];
    float e = fmaf(xs, aA_s[(s << 2) + hh], aB_s[(s << 2) + hh]) + er;
    e = e > 0.f ? e : 0.2f * e;
    float p = __expf(e - m);
    den += p;
    const float4* Ar = (const float4*)(Ag + (s << 6) + (hh << 4));
    const float4* Br = (const float4*)(Bg + (s << 6) + (hh << 4));
#pragma unroll
    for (int c = 0; c < 4; ++c) {
      float4 a4 = Ar[c], b4 = Br[c];
      acc[c*4+0] = fmaf(p, fmaf(xs, a4.x, b4.x), acc[c*4+0]);
      acc[c*4+1] = fmaf(p, fmaf(xs, a4.y, b4.y), acc[c*4+1]);
      acc[c*4+2] = fmaf(p, fmaf(xs, a4.z, b4.z), acc[c*4+2]);
      acc[c*4+3] = fmaf(p, fmaf(xs, a4.w, b4.w), acc[c*4+3]);
    }
  }
  float invd = __builtin_amdgcn_rcpf(den);
  __syncthreads();                      // all x reads done before overwrite
#pragma unroll
  for (int c = 0; c < 4; ++c) {
    float4 o;
    o.x = acc[c*4+0] * invd; o.y = acc[c*4+1] * invd;
    o.z = acc[c*4+2] * invd; o.w = acc[c*4+3] * invd;
    ((float4*)slab)[(tts << 4) + (((hh << 2) + c) ^ s7)] = o;  // g over x
  }
  __syncthreads();
  __builtin_amdgcn_sched_barrier(0);    // keep weight loads out of GAT phase

  // ---- GRU serial loop; thread (row=h-dim, kg=k-quarter) ----
  int row = t >> 2, kg = t & 3;
  const float* Wi = W_ih + f * 12288;
  const float* Wh = W_hh + f * 12288;
  float wi0[16], wi1[16], wi2[16], wh0[16], wh1[16], wh2[16];
#pragma unroll
  for (int c = 0; c < 4; ++c) {
    *(float4*)&wi0[c*4] = ((const float4*)(Wi + (row << 6)          + (kg << 4)))[c];
    *(float4*)&wi1[c*4] = ((const float4*)(Wi + ((64 + row) << 6)   + (kg << 4)))[c];
    *(float4*)&wi2[c*4] = ((const float4*)(Wi + ((128 + row) << 6)  + (kg << 4)))[c];
    *(float4*)&wh0[c*4] = ((const float4*)(Wh + (row << 6)          + (kg << 4)))[c];
    *(float4*)&wh1[c*4] = ((const float4*)(Wh + ((64 + row) << 6)   + (kg << 4)))[c];
    *(float4*)&wh2[c*4] = ((const float4*)(Wh + ((128 + row) << 6)  + (kg << 4)))[c];
  }
  float bR  = b_ih[f*192 + row]       + b_hh[f*192 + row];
  float bZ  = b_ih[f*192 + 64 + row]  + b_hh[f*192 + 64 + row];
  float bXN = b_ih[f*192 + 128 + row];
  float bHN = b_hh[f*192 + 128 + row];
  float bdec = b_dec[f];
  size_t hidbase = (size_t)b * 262144 + (f << 6);
  float hreg = 0.f;

  for (int ts2 = 0; ts2 < 64; ++ts2) {
    int cur = ts2 & 1, s7b = ts2 & 7;
    float ar = 0.f, az = 0.f, axn = 0.f, ahn = 0.f;
#pragma unroll
    for (int c = 0; c < 4; ++c) {
      float4 xv = ((const float4*)slab)[(ts2 << 4) + (((kg << 2) + c) ^ s7b)];
      float4 hv = ((const float4*)&h_s[cur][0])[(kg << 2) + c];
      ar  = fmaf(xv.x, wi0[c*4+0], ar);  ar  = fmaf(xv.y, wi0[c*4+1], ar);
      ar  = fmaf(xv.z, wi0[c*4+2], ar);  ar  = fmaf(xv.w, wi0[c*4+3], ar);
      az  = fmaf(xv.x, wi1[c*4+0], az);  az  = fmaf(xv.y, wi1[c*4+1], az);
      az  = fmaf(xv.z, wi1[c*4+2], az);  az  = fmaf(xv.w, wi1[c*4+3], az);
      axn = fmaf(xv.x, wi2[c*4+0], axn); axn = fmaf(xv.y, wi2[c*4+1], axn);
      axn = fmaf(xv.z, wi2[c*4+2], axn); axn = fmaf(xv.w, wi2[c*4+3], axn);
      ar  = fmaf(hv.x, wh0[c*4+0], ar);  ar  = fmaf(hv.y, wh0[c*4+1], ar);
      ar  = fmaf(hv.z, wh0[c*4+2], ar);  ar  = fmaf(hv.w, wh0[c*4+3], ar);
      az  = fmaf(hv.x, wh1[c*4+0], az);  az  = fmaf(hv.y, wh1[c*4+1], az);
      az  = fmaf(hv.z, wh1[c*4+2], az);  az  = fmaf(hv.w, wh1[c*4+3], az);
      ahn = fmaf(hv.x, wh2[c*4+0], ahn); ahn = fmaf(hv.y, wh2[c*4+1], ahn);
      ahn = fmaf(hv.z, wh2[c*4+2], ahn); ahn = fmaf(hv.w, wh2[c*4+3], ahn);
    }
    ar = qsum(ar); az = qsum(az); axn = qsum(axn); ahn = qsum(ahn);
    float r = __builtin_amdgcn_rcpf(1.f + __expf(-(ar + bR)));
    float z = __builtin_amdgcn_rcpf(1.f + __expf(-(az + bZ)));
    float pre = fmaf(r, ahn + bHN, axn + bXN);
    float nn = 1.f - 2.f * __builtin_amdgcn_rcpf(1.f + __expf(2.f * pre));
    float hnew = fmaf(z, hreg - nn, nn);
    hreg = hnew;
    if (kg == 0) h_s[cur ^ 1][row] = hnew;
    if (kg == 1) hbuf[(ts2 >> 3) & 1][s7b][row] = hnew;
    __syncthreads();
    if (s7b == 7) {                      // flush 8 steps of h + decode
      int gsel = (ts2 >> 3) & 1, ts0 = ts2 - 7;
      if (t < 128) {
        int i = t >> 4, j = t & 15;
        float4 hv4 = ((const float4*)&hbuf[gsel][i][0])[j];
        *(float4*)&hid[hidbase + (size_t)(ts0 + i) * 4096 + (j << 2)] = hv4;
      }
      int i2 = t >> 5, j2 = t & 31;
      float wd0 = W_dec[(f << 6) + j2];
      float wd1 = W_dec[(f << 6) + 32 + j2];
      float part = hbuf[gsel][i2][j2] * wd0 + hbuf[gsel][i2][j2 + 32] * wd1;
      part += __shfl_xor(part, 1);  part += __shfl_xor(part, 2);
      part += __shfl_xor(part, 4);  part += __shfl_xor(part, 8);
      part += __shfl_xor(part, 16);
      if (j2 == 0) ans[((b << 6) + ts0 + i2) * 64 + f] = part + bdec;
    }
  }
}

extern "C" void kernel_launch(void* const* d_in, const int* in_sizes, int n_in,
                              void* d_out, int out_size, void* d_ws, size_t ws_size,
                              hipStream_t stream) {
  const float* hist   = (const float*)d_in[0];
  const int* src      = (const int*)d_in[1];
  const int* dst      = (const int*)d_in[2];
  const float* W_enc  = (const float*)d_in[3];
  const float* b_enc  = (const float*)d_in[4];
  const float* W_gat  = (const float*)d_in[5];
  const float* attn_l = (const float*)d_in[6];
  const float* attn_r = (const float*)d_in[7];
  const float* b_gat  = (const float*)d_in[8];
  const float* W_ih   = (const float*)d_in[9];
  const float* W_hh   = (const float*)d_in[10];
  const float* b_ih   = (const float*)d_in[11];
  const float* b_hh   = (const float*)d_in[12];
  const float* W_dec  = (const float*)d_in[13];
  const float* b_dec  = (const float*)d_in[14];
  int E = in_sizes[1];

  float* ans = (float*)d_out;
  float* hid = (float*)d_out + Bb * Tt * Ff;   // [B,T,F,H]

  int* off   = (int*)d_ws;                     // 65 used (reserve 256)
  int* csr   = off + 256;                      // E used (reserve 2048)
  float* A   = (float*)(csr + 2048);           // 4096
  float* Bc  = A + 4096;                       // 4096 (b_gat folded)
  float* aA  = Bc + 4096;                      // 256
  float* aB  = aA + 256;
  float* rA  = aB + 256;
  float* rB  = rA + 256;

  hipLaunchKernelGGL(k0_prep, dim3(1), dim3(256), 0, stream,
                     src, dst, E, W_enc, b_enc, W_gat, attn_l, attn_r, b_gat,
                     off, csr, A, Bc, aA, aB, rA, rB);
  hipLaunchKernelGGL(k_fused, dim3(Ff * Bb), dim3(256), 0, stream,
                     hist, A, Bc, aA, aB, rA, rB, off, csr,
                     W_ih, W_hh, b_ih, b_hh, W_dec, b_dec, hid, ans);
}